// Round 4
// baseline (1003.897 us; speedup 1.0000x reference)
//
#include <hip/hip_runtime.h>

#define NTOK 49
#define HEADS 6
#define CDIM 192
#define NWIN 4096

typedef unsigned short u16;
typedef unsigned int u32;
typedef unsigned long long u64;
typedef __attribute__((ext_vector_type(8))) __bf16 bf16x8;
typedef __attribute__((ext_vector_type(4))) float floatx4;
typedef __attribute__((ext_vector_type(4))) u32 u32x4;

struct __attribute__((aligned(4))) F4 { float f[4]; };

__device__ __forceinline__ u16 f2bf(float f) {
  union { float f; u32 u; } v; v.f = f;
  u32 u = v.u;
  u = (u + 0x7FFFu + ((u >> 16) & 1u)) >> 16;
  return (u16)u;
}
__device__ __forceinline__ void st4bf(u16* p, float a, float b, float c, float d) {
  u64 t = (u64)f2bf(a) | ((u64)f2bf(b) << 16) | ((u64)f2bf(c) << 32) | ((u64)f2bf(d) << 48);
  *(u64*)p = t;
}
__device__ __forceinline__ float bf2f(u16 u) {
  union { u32 u; float f; } v; v.u = ((u32)u) << 16;
  return v.f;
}
__device__ __forceinline__ float bflo(u32 u) {
  union { u32 u; float f; } v; v.u = u << 16;
  return v.f;
}
__device__ __forceinline__ float bfhi(u32 u) {
  union { u32 u; float f; } v; v.u = u & 0xffff0000u;
  return v.f;
}
__device__ __forceinline__ u32 pack2bf(float lo, float hi) {
  return (u32)f2bf(lo) | ((u32)f2bf(hi) << 16);
}

// ---------------- prep: weights->bf16, bias gather ----------------
__global__ __launch_bounds__(256)
void wprep(const float* __restrict__ Wq, const float* __restrict__ Wk,
           const float* __restrict__ Wv, const float* __restrict__ Wp,
           const float* __restrict__ rpb, const int* __restrict__ rel,
           u16* __restrict__ w_bf, float* __restrict__ bias) {
  const int tid = blockIdx.x * blockDim.x + threadIdx.x;
  const int stride = gridDim.x * blockDim.x;
  for (int i = tid; i < 4 * CDIM * CDIM; i += stride) {
    const int p = i / (CDIM * CDIM), e = i % (CDIM * CDIM);
    float v = (p == 0) ? Wq[e] : (p == 1) ? Wk[e] : (p == 2) ? Wv[e] : Wp[e];
    w_bf[i] = f2bf(v);
  }
  for (int i = tid; i < HEADS * NTOK * NTOK; i += stride) {
    const int h = i / (NTOK * NTOK), nm = i % (NTOK * NTOK);
    bias[i] = rpb[rel[nm] * HEADS + h];
  }
}

// ---------------- K1: QKV projection GEMM (no LDS, no barriers) ----------------
// Qg/Kg: [w][h][49][32] bf16 ; Vt: [w][192chan][64tok] bf16
__global__ __launch_bounds__(256, 3)
void k1_qkv(const float* __restrict__ x, const u16* __restrict__ w_bf,
            u16* __restrict__ Qg, u16* __restrict__ Kg, u16* __restrict__ Vt) {
  const int w = blockIdx.x;
  const int wave = threadIdx.x >> 6;
  const int lane = threadIdx.x & 63;
  const int g = lane >> 4, nl = lane & 15;
  const float* xw = x + (size_t)w * (NTOK * CDIM);

  bf16x8 xf[4][6];
#pragma unroll
  for (int nt = 0; nt < 4; ++nt) {
    const int tok = nt * 16 + nl;
#pragma unroll
    for (int k = 0; k < 6; ++k) {
      if (tok < NTOK) {
        const float4 lo = *(const float4*)(xw + tok * CDIM + k * 32 + g * 8);
        const float4 hi = *(const float4*)(xw + tok * CDIM + k * 32 + g * 8 + 4);
        u32x4 t;
        t[0] = pack2bf(lo.x, lo.y); t[1] = pack2bf(lo.z, lo.w);
        t[2] = pack2bf(hi.x, hi.y); t[3] = pack2bf(hi.z, hi.w);
        xf[nt][k] = __builtin_bit_cast(bf16x8, t);
      } else {
        u32x4 t = {0u, 0u, 0u, 0u};
        xf[nt][k] = __builtin_bit_cast(bf16x8, t);
      }
    }
  }

  for (int t = wave; t < 36; t += 4) {
    const int p = t / 12, c = t % 12;
    const u16* wb = w_bf + p * (CDIM * CDIM) + (c * 16 + nl) * CDIM + g * 8;
    bf16x8 wf[6];
#pragma unroll
    for (int k = 0; k < 6; ++k) wf[k] = *(const bf16x8*)(wb + k * 32);
    floatx4 acc[4];
#pragma unroll
    for (int nt = 0; nt < 4; ++nt) acc[nt] = (floatx4){0.f, 0.f, 0.f, 0.f};
    if (p < 2) {
      // Q^T/K^T tile: A=W rows (out-chans), B=X^T (cols=toks). C: col=tok, rows=4 consecutive chans.
#pragma unroll
      for (int k = 0; k < 6; ++k)
#pragma unroll
        for (int nt = 0; nt < 4; ++nt)
          acc[nt] = __builtin_amdgcn_mfma_f32_16x16x32_bf16(wf[k], xf[nt][k], acc[nt], 0, 0, 0);
      const int h = c >> 1, half = c & 1;
      u16* dst = (p == 0 ? Qg : Kg) + (size_t)(w * 6 + h) * (NTOK * 32);
#pragma unroll
      for (int nt = 0; nt < 4; ++nt) {
        const int tok = nt * 16 + nl;
        if (tok < NTOK)
          st4bf(dst + tok * 32 + half * 16 + g * 4,
                acc[nt][0], acc[nt][1], acc[nt][2], acc[nt][3]);
      }
    } else {
      // V tile: A=X (rows toks), B=Wv^T (cols=chans). C: col=chan(nl), rows=4 consecutive toks
      // -> contiguous b64 store into Vt[chan][tok].
#pragma unroll
      for (int k = 0; k < 6; ++k)
#pragma unroll
        for (int nt = 0; nt < 4; ++nt)
          acc[nt] = __builtin_amdgcn_mfma_f32_16x16x32_bf16(xf[nt][k], wf[k], acc[nt], 0, 0, 0);
      u16* dst = Vt + ((size_t)w * CDIM + c * 16 + nl) * 64;
#pragma unroll
      for (int nt = 0; nt < 4; ++nt)
        st4bf(dst + nt * 16 + g * 4, acc[nt][0], acc[nt][1], acc[nt][2], acc[nt][3]);
    }
  }
}

// ---------------- K2: attention + out-projection (wave = head) ----------------
// LDS: AO [64][200] u16 (25600) | P [6][16][72] u16 (13824) | nrm [6][128] f32 (3072)
#define K2_LDS (25600 + 13824 + 3072)
__global__ __launch_bounds__(384, 4)
void k2_attn(const u16* __restrict__ Qg, const u16* __restrict__ Kg,
             const u16* __restrict__ Vt, const float* __restrict__ mask,
             const float* __restrict__ d_l, const float* __restrict__ temp,
             const float* __restrict__ bias, const u16* __restrict__ w_bf,
             float* __restrict__ out) {
  extern __shared__ __align__(16) char smem[];
  u16* AO = (u16*)smem;                          // [64][200]
  u16* Pall = (u16*)(smem + 25600);              // [6][16][72]
  float* nrm = (float*)(smem + 25600 + 13824);   // [6][128]: [0..63]=krec, [64..127]=qrec

  const int w = blockIdx.x;
  const int h = threadIdx.x >> 6;  // wave = head
  const int lane = threadIdx.x & 63;
  const int g = lane >> 4, nl = lane & 15;
  const float dl = d_l[w];
  const float tdl = temp[h] * dl;
  const size_t qkbase = (size_t)(w * 6 + h) * (NTOK * 32);

  // --- per-head norms: lane = token, coalesced 64B row reads
  {
    const u16* krow = Kg + qkbase + lane * 32;
    const u16* qrow = Qg + qkbase + lane * 32;
    float ssk = 0.f, ssq = 0.f;
#pragma unroll
    for (int q4 = 0; q4 < 4; ++q4) {
      const u32x4 kk = *(const u32x4*)(krow + q4 * 8);
      const u32x4 qq = *(const u32x4*)(qrow + q4 * 8);
#pragma unroll
      for (int e = 0; e < 4; ++e) {
        const float k0 = bflo(kk[e]), k1 = bfhi(kk[e]);
        const float q0 = bflo(qq[e]), q1 = bfhi(qq[e]);
        ssk = fmaf(k0, k0, fmaf(k1, k1, ssk));
        ssq = fmaf(q0, q0, fmaf(q1, q1, ssq));
      }
    }
    nrm[h * 128 + lane] = 1.f / fmaxf(sqrtf(ssk), 1e-12f);
    nrm[h * 128 + 64 + lane] = 1.f / fmaxf(sqrtf(ssq), 1e-12f);
  }

  u16* Pb = Pall + h * (16 * 72);
  bf16x8 kf[4];
#pragma unroll
  for (int rt = 0; rt < 4; ++rt)
    kf[rt] = *(const bf16x8*)(Kg + qkbase + (rt * 16 + nl) * 32 + g * 8);
  const int wm = w & (NWIN - 1);

  for (int nt = 0; nt < 4; ++nt) {
    const int n = nt * 16 + nl;
    const int ncl = n < NTOK ? n : NTOK - 1;
    const bf16x8 qf = *(const bf16x8*)(Qg + qkbase + n * 32 + g * 8);
    floatx4 sacc[4];
#pragma unroll
    for (int rt = 0; rt < 4; ++rt)
      sacc[rt] = __builtin_amdgcn_mfma_f32_16x16x32_bf16(kf[rt], qf, (floatx4){0.f, 0.f, 0.f, 0.f}, 0, 0, 0);
    const float qr = nrm[h * 128 + 64 + n] * tdl;
    const float* brow = bias + (h * NTOK + ncl) * NTOK;
    const float* mrow = mask + ((size_t)wm * NTOK + ncl) * NTOK;
    float L[4][4];
    float pmax = -1e30f;
#pragma unroll
    for (int rt = 0; rt < 3; ++rt) {
      const F4 b4 = *(const F4*)(brow + rt * 16 + g * 4);
      const F4 m4 = *(const F4*)(mrow + rt * 16 + g * 4);
      const F4 kr = *(const F4*)(nrm + h * 128 + rt * 16 + g * 4);
#pragma unroll
      for (int r = 0; r < 4; ++r) {
        const float lv = fmaf(sacc[rt][r] * kr.f[r], qr, (b4.f[r] + m4.f[r]) * dl);
        L[rt][r] = lv;
        pmax = fmaxf(pmax, lv);
      }
    }
    {  // rt=3: only m=48 real (g==0, r==0)
      const float lv48 = fmaf(sacc[3][0] * nrm[h * 128 + 48], qr, (brow[48] + mrow[48]) * dl);
      L[3][0] = L[3][1] = L[3][2] = L[3][3] = -1e30f;
      if (g == 0) { L[3][0] = lv48; pmax = fmaxf(pmax, lv48); }
    }
    pmax = fmaxf(pmax, __shfl_xor(pmax, 16));
    pmax = fmaxf(pmax, __shfl_xor(pmax, 32));
    float psum = 0.f;
#pragma unroll
    for (int rt = 0; rt < 4; ++rt)
#pragma unroll
      for (int r = 0; r < 4; ++r) {
        const float e = __expf(L[rt][r] - pmax);
        L[rt][r] = e;
        psum += e;
      }
    psum += __shfl_xor(psum, 16);
    psum += __shfl_xor(psum, 32);
    const float rinv = 1.0f / psum;
#pragma unroll
    for (int rt = 0; rt < 4; ++rt)
      st4bf(Pb + nl * 72 + rt * 16 + g * 4,
            L[rt][0] * rinv, L[rt][1] * rinv, L[rt][2] * rinv, L[rt][3] * rinv);
    // PV: O^T = Vt * P
    floatx4 oacc[2];
    oacc[0] = (floatx4){0.f, 0.f, 0.f, 0.f};
    oacc[1] = (floatx4){0.f, 0.f, 0.f, 0.f};
#pragma unroll
    for (int ks = 0; ks < 2; ++ks) {
      const bf16x8 pfr = *(const bf16x8*)(Pb + nl * 72 + ks * 32 + g * 8);
#pragma unroll
      for (int dt = 0; dt < 2; ++dt) {
        const bf16x8 vf = *(const bf16x8*)(Vt + ((size_t)w * CDIM + h * 32 + dt * 16 + nl) * 64 + ks * 32 + g * 8);
        oacc[dt] = __builtin_amdgcn_mfma_f32_16x16x32_bf16(vf, pfr, oacc[dt], 0, 0, 0);
      }
    }
#pragma unroll
    for (int dt = 0; dt < 2; ++dt)
      st4bf(AO + n * 200 + h * 32 + dt * 16 + g * 4,
            oacc[dt][0], oacc[dt][1], oacc[dt][2], oacc[dt][3]);
  }
  __syncthreads();

  // --- out-proj: out^T tiles, 48 tasks over 6 waves
  {
    float* outb = out + (size_t)w * (NTOK * CDIM);
    const u16* wpb = w_bf + 3 * (CDIM * CDIM);
    for (int t = h; t < 48; t += 6) {
      const int o = t >> 2, nt = t & 3;
      bf16x8 af[6], wfp[6];
#pragma unroll
      for (int k = 0; k < 6; ++k)
        af[k] = *(const bf16x8*)(AO + (nt * 16 + nl) * 200 + k * 32 + g * 8);
#pragma unroll
      for (int k = 0; k < 6; ++k)
        wfp[k] = *(const bf16x8*)(wpb + (o * 16 + nl) * CDIM + k * 32 + g * 8);
      floatx4 acc = (floatx4){0.f, 0.f, 0.f, 0.f};
#pragma unroll
      for (int k = 0; k < 6; ++k)
        acc = __builtin_amdgcn_mfma_f32_16x16x32_bf16(af[k], wfp[k], acc, 0, 0, 0);
#pragma unroll
      for (int r = 0; r < 4; ++r) {
        const int tok = nt * 16 + g * 4 + r;
        if (tok < NTOK) outb[tok * CDIM + o * 16 + nl] = acc[r];
      }
    }
  }
}

// ---------------- fallback: R1 fused kernel (proven, used if ws too small) ----------------
#define FB_OFF_X 0
#define FB_OFF_Q 25600
#define FB_OFF_K 51200
#define FB_OFF_V 76800
#define FB_OFF_P 104448
#define FB_LDS_BYTES 122880

__global__ __launch_bounds__(512, 2)
void wattn_fused(const float* __restrict__ x, const float* __restrict__ mask,
                 const float* __restrict__ d_l, const float* __restrict__ temp,
                 const u16* __restrict__ w_bf, const float* __restrict__ bias,
                 float* __restrict__ out) {
  extern __shared__ __align__(16) char smem[];
  u16* Xb = (u16*)(smem + FB_OFF_X);
  u16* Qn = (u16*)(smem + FB_OFF_Q);
  u16* Kn = (u16*)(smem + FB_OFF_K);
  u16* Vt = (u16*)(smem + FB_OFF_V);
  u16* Pw = (u16*)(smem + FB_OFF_P);

  const int b = blockIdx.x;
  const int tid = threadIdx.x;
  const int wave = tid >> 6;
  const int lane = tid & 63;
  const int g = lane >> 4;
  const int nl = lane & 15;

  {
    const float* xb = x + (size_t)b * (NTOK * CDIM);
    for (int i = tid; i < NTOK * CDIM / 4; i += 512) {
      const int n = i / 48;
      const int c = (i - n * 48) * 4;
      const float4 v = *(const float4*)(xb + n * CDIM + c);
      st4bf(Xb + n * 200 + c, v.x, v.y, v.z, v.w);
    }
    for (int i = tid; i < 15 * 48; i += 512) {
      const int n = 49 + i / 48;
      const int c = (i % 48) * 4;
      *(u64*)(Xb + n * 200 + c) = 0ull;
    }
  }
  __syncthreads();

  {
    bf16x8 xf[4][6];
#pragma unroll
    for (int nt = 0; nt < 4; ++nt)
#pragma unroll
      for (int k = 0; k < 6; ++k)
        xf[nt][k] = *(const bf16x8*)(Xb + (nt * 16 + nl) * 200 + k * 32 + g * 8);

    for (int u = wave; u < 36; u += 8) {
      const int p = u / 12, o = u % 12;
      const u16* wb = w_bf + p * (CDIM * CDIM) + (o * 16 + nl) * CDIM + g * 8;
      bf16x8 wf[6];
#pragma unroll
      for (int k = 0; k < 6; ++k) wf[k] = *(const bf16x8*)(wb + k * 32);
      floatx4 acc[4];
#pragma unroll
      for (int nt = 0; nt < 4; ++nt) acc[nt] = (floatx4){0.f, 0.f, 0.f, 0.f};
      if (p < 2) {
#pragma unroll
        for (int k = 0; k < 6; ++k)
#pragma unroll
          for (int nt = 0; nt < 4; ++nt)
            acc[nt] = __builtin_amdgcn_mfma_f32_16x16x32_bf16(wf[k], xf[nt][k], acc[nt], 0, 0, 0);
        u16* dst = (p == 0 ? Qn : Kn);
#pragma unroll
        for (int nt = 0; nt < 4; ++nt)
          st4bf(dst + (nt * 16 + nl) * 200 + o * 16 + g * 4,
                acc[nt][0], acc[nt][1], acc[nt][2], acc[nt][3]);
      } else {
#pragma unroll
        for (int k = 0; k < 6; ++k)
#pragma unroll
          for (int nt = 0; nt < 4; ++nt)
            acc[nt] = __builtin_amdgcn_mfma_f32_16x16x32_bf16(xf[nt][k], wf[k], acc[nt], 0, 0, 0);
#pragma unroll
        for (int nt = 0; nt < 4; ++nt)
          st4bf(Vt + (o * 16 + nl) * 72 + nt * 16 + g * 4,
                acc[nt][0], acc[nt][1], acc[nt][2], acc[nt][3]);
      }
    }
  }
  __syncthreads();

  {
    const int sub = tid & 3;
    for (int ru = tid >> 2; ru < 2 * HEADS * NTOK; ru += 128) {
      const int t = ru / (HEADS * NTOK);
      const int rem = ru - t * (HEADS * NTOK);
      const int h = rem / NTOK, n = rem - h * NTOK;
      u16* base = (t == 0 ? Qn : Kn) + n * 200 + h * 32 + sub * 8;
      u64 lo = *(u64*)base;
      u64 hi = *(u64*)(base + 4);
      float f[8];
#pragma unroll
      for (int e = 0; e < 4; ++e) f[e] = bf2f((u16)(lo >> (16 * e)));
#pragma unroll
      for (int e = 0; e < 4; ++e) f[4 + e] = bf2f((u16)(hi >> (16 * e)));
      float ss = 0.f;
#pragma unroll
      for (int e = 0; e < 8; ++e) ss += f[e] * f[e];
      ss += __shfl_xor(ss, 1);
      ss += __shfl_xor(ss, 2);
      const float inv = 1.0f / fmaxf(sqrtf(ss), 1e-12f);
      st4bf(base, f[0] * inv, f[1] * inv, f[2] * inv, f[3] * inv);
      st4bf(base + 4, f[4] * inv, f[5] * inv, f[6] * inv, f[7] * inv);
    }
  }
  __syncthreads();

  {
    const float dl = d_l[b];
    const int wmask = b & (NWIN - 1);
    u16* Pb = Pw + wave * (16 * 72);
    for (int t = wave; t < 24; t += 8) {
      const int h = t >> 2, nt2 = t & 3;
      const int n = nt2 * 16 + nl;
      const int ncl = n < 49 ? n : 48;
      const float tdl = temp[h] * dl;
      const bf16x8 qf = *(const bf16x8*)(Qn + n * 200 + h * 32 + g * 8);
      floatx4 sacc[4];
#pragma unroll
      for (int rt = 0; rt < 4; ++rt) {
        const bf16x8 kf = *(const bf16x8*)(Kn + (rt * 16 + nl) * 200 + h * 32 + g * 8);
        sacc[rt] = __builtin_amdgcn_mfma_f32_16x16x32_bf16(kf, qf, (floatx4){0.f, 0.f, 0.f, 0.f}, 0, 0, 0);
      }
      const float* brow = bias + (h * NTOK + ncl) * NTOK;
      const float* mrow = mask + ((size_t)wmask * NTOK + ncl) * NTOK;
      float L[4][4];
      float pmax = -1e30f;
#pragma unroll
      for (int rt = 0; rt < 4; ++rt)
#pragma unroll
        for (int r = 0; r < 4; ++r) {
          const int m = rt * 16 + g * 4 + r;
          const int mcl = m < 49 ? m : 48;
          const float bm = (brow[mcl] + mrow[mcl]) * dl;
          float lv = fmaf(sacc[rt][r], tdl, bm);
          lv = (m < 49) ? lv : -1e30f;
          L[rt][r] = lv;
          pmax = fmaxf(pmax, lv);
        }
      pmax = fmaxf(pmax, __shfl_xor(pmax, 16));
      pmax = fmaxf(pmax, __shfl_xor(pmax, 32));
      float psum = 0.f;
#pragma unroll
      for (int rt = 0; rt < 4; ++rt)
#pragma unroll
        for (int r = 0; r < 4; ++r) {
          const int m = rt * 16 + g * 4 + r;
          const float e = (m < 49) ? __expf(L[rt][r] - pmax) : 0.f;
          L[rt][r] = e;
          psum += e;
        }
      psum += __shfl_xor(psum, 16);
      psum += __shfl_xor(psum, 32);
      const float rinv = 1.0f / psum;
#pragma unroll
      for (int rt = 0; rt < 4; ++rt)
        st4bf(Pb + nl * 72 + rt * 16 + g * 4,
              L[rt][0] * rinv, L[rt][1] * rinv, L[rt][2] * rinv, L[rt][3] * rinv);
      floatx4 oacc[2];
      oacc[0] = (floatx4){0.f, 0.f, 0.f, 0.f};
      oacc[1] = (floatx4){0.f, 0.f, 0.f, 0.f};
#pragma unroll
      for (int ks = 0; ks < 2; ++ks) {
        const bf16x8 pf = *(const bf16x8*)(Pb + nl * 72 + ks * 32 + g * 8);
#pragma unroll
        for (int dt = 0; dt < 2; ++dt) {
          const bf16x8 vf = *(const bf16x8*)(Vt + (h * 32 + dt * 16 + nl) * 72 + ks * 32 + g * 8);
          oacc[dt] = __builtin_amdgcn_mfma_f32_16x16x32_bf16(vf, pf, oacc[dt], 0, 0, 0);
        }
      }
#pragma unroll
      for (int dt = 0; dt < 2; ++dt)
        st4bf(Xb + n * 200 + h * 32 + dt * 16 + g * 4,
              oacc[dt][0], oacc[dt][1], oacc[dt][2], oacc[dt][3]);
    }
  }
  __syncthreads();

  {
    bf16x8 af[4][6];
#pragma unroll
    for (int nt = 0; nt < 4; ++nt)
#pragma unroll
      for (int k = 0; k < 6; ++k)
        af[nt][k] = *(const bf16x8*)(Xb + (nt * 16 + nl) * 200 + k * 32 + g * 8);
    float* outb = out + (size_t)b * (NTOK * CDIM);
    const u16* wpb = w_bf + 3 * (CDIM * CDIM);
    for (int o = wave; o < 12; o += 8) {
      const u16* wb = wpb + (o * 16 + nl) * CDIM + g * 8;
      bf16x8 wf[6];
#pragma unroll
      for (int k = 0; k < 6; ++k) wf[k] = *(const bf16x8*)(wb + k * 32);
      floatx4 acc[4];
#pragma unroll
      for (int nt = 0; nt < 4; ++nt) acc[nt] = (floatx4){0.f, 0.f, 0.f, 0.f};
#pragma unroll
      for (int k = 0; k < 6; ++k)
#pragma unroll
        for (int nt = 0; nt < 4; ++nt)
          acc[nt] = __builtin_amdgcn_mfma_f32_16x16x32_bf16(wf[k], af[nt][k], acc[nt], 0, 0, 0);
#pragma unroll
      for (int nt = 0; nt < 4; ++nt) {
        const int n = nt * 16 + nl;
        if (n < 49) {
          float4 v;
          v.x = acc[nt][0]; v.y = acc[nt][1]; v.z = acc[nt][2]; v.w = acc[nt][3];
          *(float4*)(outb + n * CDIM + o * 16 + g * 4) = v;
        }
      }
    }
  }
}

extern "C" void kernel_launch(void* const* d_in, const int* in_sizes, int n_in,
                              void* d_out, int out_size, void* d_ws, size_t ws_size,
                              hipStream_t stream) {
  const float* x    = (const float*)d_in[0];
  const float* mask = (const float*)d_in[1];
  const float* dl   = (const float*)d_in[2];
  const float* Wq   = (const float*)d_in[3];
  const float* Wk   = (const float*)d_in[4];
  const float* Wv   = (const float*)d_in[5];
  const float* Wp   = (const float*)d_in[6];
  const float* temp = (const float*)d_in[7];
  const float* rpb  = (const float*)d_in[8];
  const int*   rel  = (const int*)d_in[9];
  float* o = (float*)d_out;

  // ws layout
  const size_t off_bias = 294912;                       // after w_bf
  const size_t off_q = 352768;                          // 294912+57624 rounded up
  const size_t sz_qk = (size_t)8192 * 6 * NTOK * 32 * 2 + 4096;  // +slack for padded-row reads
  const size_t off_k = off_q + sz_qk;
  const size_t off_v = off_k + sz_qk;
  const size_t sz_v = (size_t)8192 * CDIM * 64 * 2;
  const size_t need = off_v + sz_v;                     // ~510 MB

  u16* w_bf = (u16*)d_ws;
  float* bias = (float*)((char*)d_ws + off_bias);

  wprep<<<256, 256, 0, stream>>>(Wq, Wk, Wv, Wp, rpb, rel, w_bf, bias);

  if (ws_size >= need) {
    u16* Qg = (u16*)((char*)d_ws + off_q);
    u16* Kg = (u16*)((char*)d_ws + off_k);
    u16* Vt = (u16*)((char*)d_ws + off_v);
    k1_qkv<<<8192, 256, 0, stream>>>(x, w_bf, Qg, Kg, Vt);
    k2_attn<<<8192, 384, K2_LDS, stream>>>(Qg, Kg, Vt, mask, dl, temp, bias, w_bf, o);
  } else {
    (void)hipFuncSetAttribute((const void*)wattn_fused,
                              hipFuncAttributeMaxDynamicSharedMemorySize, FB_LDS_BYTES);
    wattn_fused<<<8192, 512, FB_LDS_BYTES, stream>>>(x, mask, dl, temp, w_bf, bias, o);
  }
}

// Round 5
// 787.761 us; speedup vs baseline: 1.2744x; 1.2744x over previous
//
#include <hip/hip_runtime.h>

#define NTOK 49
#define HEADS 6
#define CDIM 192
#define NWIN 4096

typedef unsigned short u16;
typedef unsigned int u32;
typedef unsigned long long u64;
typedef __attribute__((ext_vector_type(8))) __bf16 bf16x8;
typedef __attribute__((ext_vector_type(4))) float floatx4;

struct __attribute__((aligned(4))) F4 { float f[4]; };

// LDS layout (bytes), 16-wave block. Total 141312 <= 163840 (1 block/CU, 16 waves = 4/SIMD)
#define OFF_X 0         // [64][200] u16 (X, later AO)          25600
#define OFF_Q 25600     // [64][200] u16                        25600
#define OFF_K 51200     // [64][200] u16                        25600
#define OFF_V 76800     // [192][72] u16  Vt[chan][tok]         27648
#define OFF_P 104448    // [16 waves][16][72] u16               36864
#define LDS_BYTES 141312

__device__ __forceinline__ u16 f2bf(float f) {
  union { float f; u32 u; } v; v.f = f;
  u32 u = v.u;
  u = (u + 0x7FFFu + ((u >> 16) & 1u)) >> 16;
  return (u16)u;
}
__device__ __forceinline__ void st4bf(u16* p, float a, float b, float c, float d) {
  u64 t = (u64)f2bf(a) | ((u64)f2bf(b) << 16) | ((u64)f2bf(c) << 32) | ((u64)f2bf(d) << 48);
  *(u64*)p = t;
}
__device__ __forceinline__ float bf2f(u16 u) {
  union { u32 u; float f; } v; v.u = ((u32)u) << 16;
  return v.f;
}

__global__ __launch_bounds__(256)
void wprep(const float* __restrict__ Wq, const float* __restrict__ Wk,
           const float* __restrict__ Wv, const float* __restrict__ Wp,
           const float* __restrict__ rpb, const int* __restrict__ rel,
           u16* __restrict__ w_bf, float* __restrict__ bias) {
  const int tid = blockIdx.x * blockDim.x + threadIdx.x;
  const int stride = gridDim.x * blockDim.x;
  for (int i = tid; i < 4 * CDIM * CDIM; i += stride) {
    const int p = i / (CDIM * CDIM), e = i % (CDIM * CDIM);
    float v = (p == 0) ? Wq[e] : (p == 1) ? Wk[e] : (p == 2) ? Wv[e] : Wp[e];
    w_bf[i] = f2bf(v);
  }
  for (int i = tid; i < HEADS * NTOK * NTOK; i += stride) {
    const int h = i / (NTOK * NTOK), nm = i % (NTOK * NTOK);
    bias[i] = rpb[rel[nm] * HEADS + h];
  }
}

// Fused window attention: R1 structure, 16 waves (1024 thr), 1 block/CU.
__global__ __launch_bounds__(1024, 4)
void wattn_main(const float* __restrict__ x, const float* __restrict__ mask,
                const float* __restrict__ d_l, const float* __restrict__ temp,
                const u16* __restrict__ w_bf, const float* __restrict__ bias,
                float* __restrict__ out) {
  extern __shared__ __align__(16) char smem[];
  u16* Xb = (u16*)(smem + OFF_X);
  u16* Qn = (u16*)(smem + OFF_Q);
  u16* Kn = (u16*)(smem + OFF_K);
  u16* Vt = (u16*)(smem + OFF_V);
  u16* Pw = (u16*)(smem + OFF_P);

  const int b = blockIdx.x;
  const int tid = threadIdx.x;
  const int wave = tid >> 6;   // 0..15
  const int lane = tid & 63;
  const int g = lane >> 4;
  const int nl = lane & 15;

  // ---- phase 0: stage x -> bf16 LDS [64][200], zero pad rows 49..63
  {
    const float* xb = x + (size_t)b * (NTOK * CDIM);
    for (int i = tid; i < NTOK * 48; i += 1024) {
      const int n = i / 48;
      const int c = (i - n * 48) * 4;
      const float4 v = *(const float4*)(xb + n * CDIM + c);
      st4bf(Xb + n * 200 + c, v.x, v.y, v.z, v.w);
    }
    if (tid < 15 * 48) {
      const int n = NTOK + tid / 48;
      const int c = (tid % 48) * 4;
      *(u64*)(Xb + n * 200 + c) = 0ull;
    }
  }
  __syncthreads();

  // ---- phase 1: QKV projections (4-deep nt chains, 36 tasks over 16 waves)
  {
    bf16x8 xf[4][6];
#pragma unroll
    for (int nt = 0; nt < 4; ++nt)
#pragma unroll
      for (int k = 0; k < 6; ++k)
        xf[nt][k] = *(const bf16x8*)(Xb + (nt * 16 + nl) * 200 + k * 32 + g * 8);

    for (int u = wave; u < 36; u += 16) {
      const int p = u / 12, o = u % 12;
      const u16* wb = w_bf + p * (CDIM * CDIM) + (o * 16 + nl) * CDIM + g * 8;
      bf16x8 wf[6];
#pragma unroll
      for (int k = 0; k < 6; ++k) wf[k] = *(const bf16x8*)(wb + k * 32);
      floatx4 acc[4];
#pragma unroll
      for (int nt = 0; nt < 4; ++nt) acc[nt] = (floatx4){0.f, 0.f, 0.f, 0.f};
      if (p < 2) {
#pragma unroll
        for (int k = 0; k < 6; ++k)
#pragma unroll
          for (int nt = 0; nt < 4; ++nt)
            acc[nt] = __builtin_amdgcn_mfma_f32_16x16x32_bf16(wf[k], xf[nt][k], acc[nt], 0, 0, 0);
        u16* dst = (p == 0 ? Qn : Kn);
#pragma unroll
        for (int nt = 0; nt < 4; ++nt)
          st4bf(dst + (nt * 16 + nl) * 200 + o * 16 + g * 4,
                acc[nt][0], acc[nt][1], acc[nt][2], acc[nt][3]);
      } else {
#pragma unroll
        for (int k = 0; k < 6; ++k)
#pragma unroll
          for (int nt = 0; nt < 4; ++nt)
            acc[nt] = __builtin_amdgcn_mfma_f32_16x16x32_bf16(xf[nt][k], wf[k], acc[nt], 0, 0, 0);
#pragma unroll
        for (int nt = 0; nt < 4; ++nt)
          st4bf(Vt + (o * 16 + nl) * 72 + nt * 16 + g * 4,
                acc[nt][0], acc[nt][1], acc[nt][2], acc[nt][3]);
      }
    }
  }
  __syncthreads();

  // ---- phase 2: l2-normalize Q,K rows (4 lanes per (tensor,head,token))
  {
    const int sub = tid & 3;
    for (int ru = tid >> 2; ru < 2 * HEADS * NTOK; ru += 256) {
      const int t = ru / (HEADS * NTOK);
      const int rem = ru - t * (HEADS * NTOK);
      const int h = rem / NTOK, n = rem - h * NTOK;
      u16* base = (t == 0 ? Qn : Kn) + n * 200 + h * 32 + sub * 8;
      u64 lo = *(u64*)base;
      u64 hi = *(u64*)(base + 4);
      float f[8];
#pragma unroll
      for (int e = 0; e < 4; ++e) f[e] = bf2f((u16)(lo >> (16 * e)));
#pragma unroll
      for (int e = 0; e < 4; ++e) f[4 + e] = bf2f((u16)(hi >> (16 * e)));
      float ss = 0.f;
#pragma unroll
      for (int e = 0; e < 8; ++e) ss += f[e] * f[e];
      ss += __shfl_xor(ss, 1);
      ss += __shfl_xor(ss, 2);
      const float inv = 1.0f / fmaxf(sqrtf(ss), 1e-12f);
      st4bf(base, f[0] * inv, f[1] * inv, f[2] * inv, f[3] * inv);
      st4bf(base + 4, f[4] * inv, f[5] * inv, f[6] * inv, f[7] * inv);
    }
  }
  __syncthreads();

  // ---- phase 3: attention per (head, n-tile): S^T = K*Q^T, softmax over m, O^T = Vt*P
  {
    const float dl = d_l[b];
    const int wmask = b & (NWIN - 1);
    u16* Pb = Pw + wave * (16 * 72);
    for (int t = wave; t < 24; t += 16) {
      const int h = t >> 2, nt2 = t & 3;
      const int n = nt2 * 16 + nl;
      const int ncl = n < NTOK ? n : NTOK - 1;
      const float tdl = temp[h] * dl;
      const bf16x8 qf = *(const bf16x8*)(Qn + n * 200 + h * 32 + g * 8);
      floatx4 sacc[4];
#pragma unroll
      for (int rt = 0; rt < 4; ++rt) {
        const bf16x8 kf = *(const bf16x8*)(Kn + (rt * 16 + nl) * 200 + h * 32 + g * 8);
        sacc[rt] = __builtin_amdgcn_mfma_f32_16x16x32_bf16(kf, qf, (floatx4){0.f, 0.f, 0.f, 0.f}, 0, 0, 0);
      }
      const float* brow = bias + (h * NTOK + ncl) * NTOK;
      const float* mrow = mask + ((size_t)wmask * NTOK + ncl) * NTOK;
      float L[4][4];
      float pmax = -1e30f;
#pragma unroll
      for (int rt = 0; rt < 3; ++rt) {
        const F4 b4 = *(const F4*)(brow + rt * 16 + g * 4);
        const F4 m4 = *(const F4*)(mrow + rt * 16 + g * 4);
#pragma unroll
        for (int r = 0; r < 4; ++r) {
          const float lv = fmaf(sacc[rt][r], tdl, (b4.f[r] + m4.f[r]) * dl);
          L[rt][r] = lv;
          pmax = fmaxf(pmax, lv);
        }
      }
      {  // rt=3: only m=48 real (g==0, r==0)
        const float lv48 = fmaf(sacc[3][0], tdl, (brow[48] + mrow[48]) * dl);
        L[3][0] = L[3][1] = L[3][2] = L[3][3] = -1e30f;
        if (g == 0) { L[3][0] = lv48; pmax = fmaxf(pmax, lv48); }
      }
      pmax = fmaxf(pmax, __shfl_xor(pmax, 16));
      pmax = fmaxf(pmax, __shfl_xor(pmax, 32));
      float psum = 0.f;
#pragma unroll
      for (int rt = 0; rt < 4; ++rt)
#pragma unroll
        for (int r = 0; r < 4; ++r) {
          const float e = __expf(L[rt][r] - pmax);
          L[rt][r] = e;
          psum += e;
        }
      psum += __shfl_xor(psum, 16);
      psum += __shfl_xor(psum, 32);
      const float rinv = 1.0f / psum;
#pragma unroll
      for (int rt = 0; rt < 4; ++rt)
        st4bf(Pb + nl * 72 + rt * 16 + g * 4,
              L[rt][0] * rinv, L[rt][1] * rinv, L[rt][2] * rinv, L[rt][3] * rinv);
      floatx4 oacc[2];
      oacc[0] = (floatx4){0.f, 0.f, 0.f, 0.f};
      oacc[1] = (floatx4){0.f, 0.f, 0.f, 0.f};
#pragma unroll
      for (int ks = 0; ks < 2; ++ks) {
        const bf16x8 pf = *(const bf16x8*)(Pb + nl * 72 + ks * 32 + g * 8);
#pragma unroll
        for (int dt = 0; dt < 2; ++dt) {
          const bf16x8 vf = *(const bf16x8*)(Vt + (h * 32 + dt * 16 + nl) * 72 + ks * 32 + g * 8);
          oacc[dt] = __builtin_amdgcn_mfma_f32_16x16x32_bf16(vf, pf, oacc[dt], 0, 0, 0);
        }
      }
#pragma unroll
      for (int dt = 0; dt < 2; ++dt)
        st4bf(Xb + n * 200 + h * 32 + dt * 16 + g * 4,
              oacc[dt][0], oacc[dt][1], oacc[dt][2], oacc[dt][3]);
    }
  }
  __syncthreads();

  // ---- phase 4: out = AO @ Wp^T (out^T = Wp * AO^T), 12 tasks over 16 waves, 4-deep
  {
    float* outb = out + (size_t)b * (NTOK * CDIM);
    const u16* wpb = w_bf + 3 * (CDIM * CDIM);
    for (int o = wave; o < 12; o += 16) {
      bf16x8 af[4][6];
#pragma unroll
      for (int nt = 0; nt < 4; ++nt)
#pragma unroll
        for (int k = 0; k < 6; ++k)
          af[nt][k] = *(const bf16x8*)(Xb + (nt * 16 + nl) * 200 + k * 32 + g * 8);
      const u16* wb = wpb + (o * 16 + nl) * CDIM + g * 8;
      bf16x8 wf[6];
#pragma unroll
      for (int k = 0; k < 6; ++k) wf[k] = *(const bf16x8*)(wb + k * 32);
      floatx4 acc[4];
#pragma unroll
      for (int nt = 0; nt < 4; ++nt) acc[nt] = (floatx4){0.f, 0.f, 0.f, 0.f};
#pragma unroll
      for (int k = 0; k < 6; ++k)
#pragma unroll
        for (int nt = 0; nt < 4; ++nt)
          acc[nt] = __builtin_amdgcn_mfma_f32_16x16x32_bf16(wf[k], af[nt][k], acc[nt], 0, 0, 0);
#pragma unroll
      for (int nt = 0; nt < 4; ++nt) {
        const int n = nt * 16 + nl;
        if (n < NTOK) {
          float4 v;
          v.x = acc[nt][0]; v.y = acc[nt][1]; v.z = acc[nt][2]; v.w = acc[nt][3];
          *(float4*)(outb + n * CDIM + o * 16 + g * 4) = v;
        }
      }
    }
  }
}

extern "C" void kernel_launch(void* const* d_in, const int* in_sizes, int n_in,
                              void* d_out, int out_size, void* d_ws, size_t ws_size,
                              hipStream_t stream) {
  const float* x    = (const float*)d_in[0];
  const float* mask = (const float*)d_in[1];
  const float* dl   = (const float*)d_in[2];
  const float* Wq   = (const float*)d_in[3];
  const float* Wk   = (const float*)d_in[4];
  const float* Wv   = (const float*)d_in[5];
  const float* Wp   = (const float*)d_in[6];
  const float* temp = (const float*)d_in[7];
  const float* rpb  = (const float*)d_in[8];
  const int*   rel  = (const int*)d_in[9];

  u16* w_bf = (u16*)d_ws;
  float* bias = (float*)((char*)d_ws + (size_t)4 * CDIM * CDIM * sizeof(u16));
  float* o = (float*)d_out;

  (void)hipFuncSetAttribute((const void*)wattn_main,
                            hipFuncAttributeMaxDynamicSharedMemorySize, LDS_BYTES);

  wprep<<<256, 256, 0, stream>>>(Wq, Wk, Wv, Wp, rpb, rel, w_bf, bias);
  wattn_main<<<8192, 1024, LDS_BYTES, stream>>>(x, mask, dl, temp, w_bf, bias, o);
}

// Round 6
// 600.142 us; speedup vs baseline: 1.6728x; 1.3126x over previous
//
#include <hip/hip_runtime.h>

#define NTOK 49
#define HEADS 6
#define CDIM 192
#define NWIN 4096

typedef unsigned short u16;
typedef unsigned int u32;
typedef unsigned long long u64;
typedef __attribute__((ext_vector_type(8))) __bf16 bf16x8;
typedef __attribute__((ext_vector_type(4))) float floatx4;

struct __attribute__((aligned(4))) F4 { float f[4]; };

// LDS layout (bytes), 12-wave block (768 thr), 1 block/CU, 3 waves/SIMD.
#define OFF_X 0         // [64][200] u16 (X, later AO)          25600
#define OFF_Q 25600     // [64][200] u16                        25600
#define OFF_K 51200     // [64][200] u16                        25600
#define OFF_V 76800     // [192][72] u16  Vt[chan][tok]         27648
#define OFF_P 104448    // [12 waves][16][72] u16               27648
#define LDS_BYTES 132096

// HW bf16 convert (RNE) — compiler emits v_cvt_pk_bf16_f32 for pairs (m240 path).
__device__ __forceinline__ u16 f2bf(float f) {
  return __builtin_bit_cast(u16, (__bf16)f);
}
__device__ __forceinline__ void st4bf(u16* p, float a, float b, float c, float d) {
  u32 lo = (u32)f2bf(a) | ((u32)f2bf(b) << 16);
  u32 hi = (u32)f2bf(c) | ((u32)f2bf(d) << 16);
  u64 t = (u64)lo | ((u64)hi << 32);
  *(u64*)p = t;
}
__device__ __forceinline__ float bf2f(u16 u) {
  union { u32 u; float f; } v; v.u = ((u32)u) << 16;
  return v.f;
}

__global__ __launch_bounds__(256)
void wprep(const float* __restrict__ Wq, const float* __restrict__ Wk,
           const float* __restrict__ Wv, const float* __restrict__ Wp,
           const float* __restrict__ rpb, const int* __restrict__ rel,
           u16* __restrict__ w_bf, float* __restrict__ bias) {
  const int tid = blockIdx.x * blockDim.x + threadIdx.x;
  const int stride = gridDim.x * blockDim.x;
  for (int i = tid; i < 4 * CDIM * CDIM; i += stride) {
    const int p = i / (CDIM * CDIM), e = i % (CDIM * CDIM);
    float v = (p == 0) ? Wq[e] : (p == 1) ? Wk[e] : (p == 2) ? Wv[e] : Wp[e];
    w_bf[i] = f2bf(v);
  }
  for (int i = tid; i < HEADS * NTOK * NTOK; i += stride) {
    const int h = i / (NTOK * NTOK), nm = i % (NTOK * NTOK);
    bias[i] = rpb[rel[nm] * HEADS + h];
  }
}

// Fused window attention: 12 waves, balanced tasks, register-diet fragment loads.
__global__ __launch_bounds__(768)
void wattn_main(const float* __restrict__ x, const float* __restrict__ mask,
                const float* __restrict__ d_l, const float* __restrict__ temp,
                const u16* __restrict__ w_bf, const float* __restrict__ bias,
                float* __restrict__ out) {
  extern __shared__ __align__(16) char smem[];
  u16* Xb = (u16*)(smem + OFF_X);
  u16* Qn = (u16*)(smem + OFF_Q);
  u16* Kn = (u16*)(smem + OFF_K);
  u16* Vt = (u16*)(smem + OFF_V);
  u16* Pw = (u16*)(smem + OFF_P);

  const int b = blockIdx.x;
  const int tid = threadIdx.x;
  const int wave = tid >> 6;   // 0..11
  const int lane = tid & 63;
  const int g = lane >> 4;
  const int nl = lane & 15;

  // ---- phase 0: stage x -> bf16 LDS [64][200], zero pad rows 49..63
  {
    const float* xb = x + (size_t)b * (NTOK * CDIM);
    for (int i = tid; i < NTOK * 48; i += 768) {
      const int n = i / 48;
      const int c = (i - n * 48) * 4;
      const float4 v = *(const float4*)(xb + n * CDIM + c);
      st4bf(Xb + n * 200 + c, v.x, v.y, v.z, v.w);
    }
    if (tid < 15 * 48) {
      const int n = NTOK + tid / 48;
      const int c = (tid % 48) * 4;
      *(u64*)(Xb + n * 200 + c) = 0ull;
    }
  }
  __syncthreads();

  // ---- phase 1: QKV projections, 36 tasks over 12 waves (3 each), per-k fragment loads
  for (int u = wave; u < 36; u += 12) {
    const int p = u / 12, o = u % 12;
    const u16* wb = w_bf + p * (CDIM * CDIM) + (o * 16 + nl) * CDIM + g * 8;
    floatx4 acc[4];
#pragma unroll
    for (int nt = 0; nt < 4; ++nt) acc[nt] = (floatx4){0.f, 0.f, 0.f, 0.f};
    if (p < 2) {
#pragma unroll
      for (int k = 0; k < 6; ++k) {
        const bf16x8 wf = *(const bf16x8*)(wb + k * 32);
#pragma unroll
        for (int nt = 0; nt < 4; ++nt) {
          const bf16x8 xk = *(const bf16x8*)(Xb + (nt * 16 + nl) * 200 + k * 32 + g * 8);
          acc[nt] = __builtin_amdgcn_mfma_f32_16x16x32_bf16(wf, xk, acc[nt], 0, 0, 0);
        }
      }
      u16* dst = (p == 0 ? Qn : Kn);
#pragma unroll
      for (int nt = 0; nt < 4; ++nt)
        st4bf(dst + (nt * 16 + nl) * 200 + o * 16 + g * 4,
              acc[nt][0], acc[nt][1], acc[nt][2], acc[nt][3]);
    } else {
#pragma unroll
      for (int k = 0; k < 6; ++k) {
        const bf16x8 wf = *(const bf16x8*)(wb + k * 32);
#pragma unroll
        for (int nt = 0; nt < 4; ++nt) {
          const bf16x8 xk = *(const bf16x8*)(Xb + (nt * 16 + nl) * 200 + k * 32 + g * 8);
          acc[nt] = __builtin_amdgcn_mfma_f32_16x16x32_bf16(xk, wf, acc[nt], 0, 0, 0);
        }
      }
#pragma unroll
      for (int nt = 0; nt < 4; ++nt)
        st4bf(Vt + (o * 16 + nl) * 72 + nt * 16 + g * 4,
              acc[nt][0], acc[nt][1], acc[nt][2], acc[nt][3]);
    }
  }
  __syncthreads();

  // ---- phase 2: l2-normalize Q,K rows (4 lanes per (tensor,head,token))
  {
    const int sub = tid & 3;
    for (int ru = tid >> 2; ru < 2 * HEADS * NTOK; ru += 192) {
      const int t = ru / (HEADS * NTOK);
      const int rem = ru - t * (HEADS * NTOK);
      const int h = rem / NTOK, n = rem - h * NTOK;
      u16* base = (t == 0 ? Qn : Kn) + n * 200 + h * 32 + sub * 8;
      u64 lo = *(u64*)base;
      u64 hi = *(u64*)(base + 4);
      float f[8];
#pragma unroll
      for (int e = 0; e < 4; ++e) f[e] = bf2f((u16)(lo >> (16 * e)));
#pragma unroll
      for (int e = 0; e < 4; ++e) f[4 + e] = bf2f((u16)(hi >> (16 * e)));
      float ss = 0.f;
#pragma unroll
      for (int e = 0; e < 8; ++e) ss += f[e] * f[e];
      ss += __shfl_xor(ss, 1);
      ss += __shfl_xor(ss, 2);
      const float inv = 1.0f / fmaxf(sqrtf(ss), 1e-12f);
      st4bf(base, f[0] * inv, f[1] * inv, f[2] * inv, f[3] * inv);
      st4bf(base + 4, f[4] * inv, f[5] * inv, f[6] * inv, f[7] * inv);
    }
  }
  __syncthreads();

  // ---- phase 3: attention, 24 tasks over 12 waves (2 each); exp2 domain (log2e folded)
  {
    const float dl = d_l[b];
    const float LOG2E = 1.442695040888963f;
    const float dl2 = dl * LOG2E;
    const int wmask = b & (NWIN - 1);
    u16* Pb = Pw + wave * (16 * 72);
    for (int t = wave; t < 24; t += 12) {
      const int h = t >> 2, nt2 = t & 3;
      const int n = nt2 * 16 + nl;
      const int ncl = n < NTOK ? n : NTOK - 1;
      const float tdl = temp[h] * dl2;
      const bf16x8 qf = *(const bf16x8*)(Qn + n * 200 + h * 32 + g * 8);
      floatx4 sacc[4];
#pragma unroll
      for (int rt = 0; rt < 4; ++rt) {
        const bf16x8 kf = *(const bf16x8*)(Kn + (rt * 16 + nl) * 200 + h * 32 + g * 8);
        sacc[rt] = __builtin_amdgcn_mfma_f32_16x16x32_bf16(kf, qf, (floatx4){0.f, 0.f, 0.f, 0.f}, 0, 0, 0);
      }
      const float* brow = bias + (h * NTOK + ncl) * NTOK;
      const float* mrow = mask + ((size_t)wmask * NTOK + ncl) * NTOK;
      float L[4][4];
      float pmax = -1e30f;
#pragma unroll
      for (int rt = 0; rt < 3; ++rt) {
        const F4 b4 = *(const F4*)(brow + rt * 16 + g * 4);
        const F4 m4 = *(const F4*)(mrow + rt * 16 + g * 4);
#pragma unroll
        for (int r = 0; r < 4; ++r) {
          const float lv = fmaf(sacc[rt][r], tdl, (b4.f[r] + m4.f[r]) * dl2);
          L[rt][r] = lv;
          pmax = fmaxf(pmax, lv);
        }
      }
      {  // rt=3: only m=48 real (g==0, r==0)
        const float lv48 = fmaf(sacc[3][0], tdl, (brow[48] + mrow[48]) * dl2);
        L[3][0] = L[3][1] = L[3][2] = L[3][3] = -1e30f;
        if (g == 0) { L[3][0] = lv48; pmax = fmaxf(pmax, lv48); }
      }
      pmax = fmaxf(pmax, __shfl_xor(pmax, 16));
      pmax = fmaxf(pmax, __shfl_xor(pmax, 32));
      float psum = 0.f;
#pragma unroll
      for (int rt = 0; rt < 4; ++rt)
#pragma unroll
        for (int r = 0; r < 4; ++r) {
          const float e = exp2f(L[rt][r] - pmax);
          L[rt][r] = e;
          psum += e;
        }
      psum += __shfl_xor(psum, 16);
      psum += __shfl_xor(psum, 32);
      const float rinv = 1.0f / psum;
#pragma unroll
      for (int rt = 0; rt < 4; ++rt)
        st4bf(Pb + nl * 72 + rt * 16 + g * 4,
              L[rt][0] * rinv, L[rt][1] * rinv, L[rt][2] * rinv, L[rt][3] * rinv);
      floatx4 oacc[2];
      oacc[0] = (floatx4){0.f, 0.f, 0.f, 0.f};
      oacc[1] = (floatx4){0.f, 0.f, 0.f, 0.f};
#pragma unroll
      for (int ks = 0; ks < 2; ++ks) {
        const bf16x8 pf = *(const bf16x8*)(Pb + nl * 72 + ks * 32 + g * 8);
#pragma unroll
        for (int dt = 0; dt < 2; ++dt) {
          const bf16x8 vf = *(const bf16x8*)(Vt + (h * 32 + dt * 16 + nl) * 72 + ks * 32 + g * 8);
          oacc[dt] = __builtin_amdgcn_mfma_f32_16x16x32_bf16(vf, pf, oacc[dt], 0, 0, 0);
        }
      }
#pragma unroll
      for (int dt = 0; dt < 2; ++dt)
        st4bf(Xb + n * 200 + h * 32 + dt * 16 + g * 4,
              oacc[dt][0], oacc[dt][1], oacc[dt][2], oacc[dt][3]);
    }
  }
  __syncthreads();

  // ---- phase 4: out = AO @ Wp^T (out^T = Wp * AO^T), 12 tasks over 12 waves, per-k loads
  {
    float* outb = out + (size_t)b * (NTOK * CDIM);
    const u16* wpb = w_bf + 3 * (CDIM * CDIM);
    for (int o = wave; o < 12; o += 12) {
      const u16* wb = wpb + (o * 16 + nl) * CDIM + g * 8;
      floatx4 acc[4];
#pragma unroll
      for (int nt = 0; nt < 4; ++nt) acc[nt] = (floatx4){0.f, 0.f, 0.f, 0.f};
#pragma unroll
      for (int k = 0; k < 6; ++k) {
        const bf16x8 wf = *(const bf16x8*)(wb + k * 32);
#pragma unroll
        for (int nt = 0; nt < 4; ++nt) {
          const bf16x8 af = *(const bf16x8*)(Xb + (nt * 16 + nl) * 200 + k * 32 + g * 8);
          acc[nt] = __builtin_amdgcn_mfma_f32_16x16x32_bf16(wf, af, acc[nt], 0, 0, 0);
        }
      }
#pragma unroll
      for (int nt = 0; nt < 4; ++nt) {
        const int n = nt * 16 + nl;
        if (n < NTOK) {
          float4 v;
          v.x = acc[nt][0]; v.y = acc[nt][1]; v.z = acc[nt][2]; v.w = acc[nt][3];
          *(float4*)(outb + n * CDIM + o * 16 + g * 4) = v;
        }
      }
    }
  }
}

extern "C" void kernel_launch(void* const* d_in, const int* in_sizes, int n_in,
                              void* d_out, int out_size, void* d_ws, size_t ws_size,
                              hipStream_t stream) {
  const float* x    = (const float*)d_in[0];
  const float* mask = (const float*)d_in[1];
  const float* dl   = (const float*)d_in[2];
  const float* Wq   = (const float*)d_in[3];
  const float* Wk   = (const float*)d_in[4];
  const float* Wv   = (const float*)d_in[5];
  const float* Wp   = (const float*)d_in[6];
  const float* temp = (const float*)d_in[7];
  const float* rpb  = (const float*)d_in[8];
  const int*   rel  = (const int*)d_in[9];

  u16* w_bf = (u16*)d_ws;
  float* bias = (float*)((char*)d_ws + (size_t)4 * CDIM * CDIM * sizeof(u16));
  float* o = (float*)d_out;

  (void)hipFuncSetAttribute((const void*)wattn_main,
                            hipFuncAttributeMaxDynamicSharedMemorySize, LDS_BYTES);

  wprep<<<256, 256, 0, stream>>>(Wq, Wk, Wv, Wp, rpb, rel, w_bf, bias);
  wattn_main<<<8192, 768, LDS_BYTES, stream>>>(x, mask, dl, temp, w_bf, bias, o);
}

// Round 7
// 580.982 us; speedup vs baseline: 1.7279x; 1.0330x over previous
//
#include <hip/hip_runtime.h>

#define NTOK 49
#define HEADS 6
#define CDIM 192
#define NWIN 4096

typedef unsigned short u16;
typedef unsigned int u32;
typedef unsigned long long u64;
typedef __attribute__((ext_vector_type(8))) __bf16 bf16x8;
typedef __attribute__((ext_vector_type(4))) float floatx4;

struct __attribute__((aligned(4))) F4 { float f[4]; };

// LDS layout (bytes), 16-wave block (1024 thr), 1 block/CU, 4 waves/SIMD.
#define OFF_X 0         // [64][200] u16 (X, later AO)          25600
#define OFF_Q 25600     // [64][200] u16                        25600
#define OFF_K 51200     // [64][200] u16                        25600
#define OFF_V 76800     // [192][72] u16  Vt[chan][tok]         27648
#define OFF_P 104448    // [16 waves][16][72] u16               36864
#define LDS_BYTES 141312

// HW bf16 convert (RNE) — compiler emits v_cvt_pk_bf16_f32 for pairs.
__device__ __forceinline__ u16 f2bf(float f) {
  return __builtin_bit_cast(u16, (__bf16)f);
}
__device__ __forceinline__ void st4bf(u16* p, float a, float b, float c, float d) {
  u32 lo = (u32)f2bf(a) | ((u32)f2bf(b) << 16);
  u32 hi = (u32)f2bf(c) | ((u32)f2bf(d) << 16);
  u64 t = (u64)lo | ((u64)hi << 32);
  *(u64*)p = t;
}
__device__ __forceinline__ float bf2f(u16 u) {
  union { u32 u; float f; } v; v.u = ((u32)u) << 16;
  return v.f;
}

__global__ __launch_bounds__(256)
void wprep(const float* __restrict__ Wq, const float* __restrict__ Wk,
           const float* __restrict__ Wv, const float* __restrict__ Wp,
           const float* __restrict__ rpb, const int* __restrict__ rel,
           u16* __restrict__ w_bf, float* __restrict__ bias) {
  const int tid = blockIdx.x * blockDim.x + threadIdx.x;
  const int stride = gridDim.x * blockDim.x;
  for (int i = tid; i < 4 * CDIM * CDIM; i += stride) {
    const int p = i / (CDIM * CDIM), e = i % (CDIM * CDIM);
    float v = (p == 0) ? Wq[e] : (p == 1) ? Wk[e] : (p == 2) ? Wv[e] : Wp[e];
    w_bf[i] = f2bf(v);
  }
  for (int i = tid; i < HEADS * NTOK * NTOK; i += stride) {
    const int h = i / (NTOK * NTOK), nm = i % (NTOK * NTOK);
    bias[i] = rpb[rel[nm] * HEADS + h];
  }
}

// Fused window attention: 16 waves, diet fragment loads, no VGPR cap (avoid R5 spills).
__global__ __launch_bounds__(1024)
void wattn_main(const float* __restrict__ x, const float* __restrict__ mask,
                const float* __restrict__ d_l, const float* __restrict__ temp,
                const u16* __restrict__ w_bf, const float* __restrict__ bias,
                float* __restrict__ out) {
  extern __shared__ __align__(16) char smem[];
  u16* Xb = (u16*)(smem + OFF_X);
  u16* Qn = (u16*)(smem + OFF_Q);
  u16* Kn = (u16*)(smem + OFF_K);
  u16* Vt = (u16*)(smem + OFF_V);
  u16* Pw = (u16*)(smem + OFF_P);

  const int b = blockIdx.x;
  const int tid = threadIdx.x;
  const int wave = tid >> 6;   // 0..15
  const int lane = tid & 63;
  const int g = lane >> 4;
  const int nl = lane & 15;

  // ---- phase 0: stage x -> bf16 LDS [64][200], zero pad rows 49..63
  {
    const float* xb = x + (size_t)b * (NTOK * CDIM);
    for (int i = tid; i < NTOK * 48; i += 1024) {
      const int n = i / 48;
      const int c = (i - n * 48) * 4;
      const float4 v = *(const float4*)(xb + n * CDIM + c);
      st4bf(Xb + n * 200 + c, v.x, v.y, v.z, v.w);
    }
    if (tid < 15 * 48) {
      const int n = NTOK + tid / 48;
      const int c = (tid % 48) * 4;
      *(u64*)(Xb + n * 200 + c) = 0ull;
    }
  }
  __syncthreads();

  // ---- phase 1: QKV projections, 36 tasks over 16 waves, per-k fragment loads
  for (int u = wave; u < 36; u += 16) {
    const int p = u / 12, o = u % 12;
    const u16* wb = w_bf + p * (CDIM * CDIM) + (o * 16 + nl) * CDIM + g * 8;
    floatx4 acc[4];
#pragma unroll
    for (int nt = 0; nt < 4; ++nt) acc[nt] = (floatx4){0.f, 0.f, 0.f, 0.f};
    if (p < 2) {
#pragma unroll
      for (int k = 0; k < 6; ++k) {
        const bf16x8 wf = *(const bf16x8*)(wb + k * 32);
#pragma unroll
        for (int nt = 0; nt < 4; ++nt) {
          const bf16x8 xk = *(const bf16x8*)(Xb + (nt * 16 + nl) * 200 + k * 32 + g * 8);
          acc[nt] = __builtin_amdgcn_mfma_f32_16x16x32_bf16(wf, xk, acc[nt], 0, 0, 0);
        }
      }
      u16* dst = (p == 0 ? Qn : Kn);
#pragma unroll
      for (int nt = 0; nt < 4; ++nt)
        st4bf(dst + (nt * 16 + nl) * 200 + o * 16 + g * 4,
              acc[nt][0], acc[nt][1], acc[nt][2], acc[nt][3]);
    } else {
#pragma unroll
      for (int k = 0; k < 6; ++k) {
        const bf16x8 wf = *(const bf16x8*)(wb + k * 32);
#pragma unroll
        for (int nt = 0; nt < 4; ++nt) {
          const bf16x8 xk = *(const bf16x8*)(Xb + (nt * 16 + nl) * 200 + k * 32 + g * 8);
          acc[nt] = __builtin_amdgcn_mfma_f32_16x16x32_bf16(xk, wf, acc[nt], 0, 0, 0);
        }
      }
#pragma unroll
      for (int nt = 0; nt < 4; ++nt)
        st4bf(Vt + (o * 16 + nl) * 72 + nt * 16 + g * 4,
              acc[nt][0], acc[nt][1], acc[nt][2], acc[nt][3]);
    }
  }
  __syncthreads();

  // ---- phase 2: l2-normalize Q,K rows (4 lanes per (tensor,head,token))
  {
    const int sub = tid & 3;
    for (int ru = tid >> 2; ru < 2 * HEADS * NTOK; ru += 256) {
      const int t = ru / (HEADS * NTOK);
      const int rem = ru - t * (HEADS * NTOK);
      const int h = rem / NTOK, n = rem - h * NTOK;
      u16* base = (t == 0 ? Qn : Kn) + n * 200 + h * 32 + sub * 8;
      u64 lo = *(u64*)base;
      u64 hi = *(u64*)(base + 4);
      float f[8];
#pragma unroll
      for (int e = 0; e < 4; ++e) f[e] = bf2f((u16)(lo >> (16 * e)));
#pragma unroll
      for (int e = 0; e < 4; ++e) f[4 + e] = bf2f((u16)(hi >> (16 * e)));
      float ss = 0.f;
#pragma unroll
      for (int e = 0; e < 8; ++e) ss += f[e] * f[e];
      ss += __shfl_xor(ss, 1);
      ss += __shfl_xor(ss, 2);
      const float inv = 1.0f / fmaxf(sqrtf(ss), 1e-12f);
      st4bf(base, f[0] * inv, f[1] * inv, f[2] * inv, f[3] * inv);
      st4bf(base + 4, f[4] * inv, f[5] * inv, f[6] * inv, f[7] * inv);
    }
  }
  __syncthreads();

  // ---- phase 3: attention, 24 tasks over 16 waves; exp2 domain (log2e folded)
  {
    const float dl = d_l[b];
    const float LOG2E = 1.442695040888963f;
    const float dl2 = dl * LOG2E;
    const int wmask = b & (NWIN - 1);
    u16* Pb = Pw + wave * (16 * 72);
    for (int t = wave; t < 24; t += 16) {
      const int h = t >> 2, nt2 = t & 3;
      const int n = nt2 * 16 + nl;
      const int ncl = n < NTOK ? n : NTOK - 1;
      const float tdl = temp[h] * dl2;
      const bf16x8 qf = *(const bf16x8*)(Qn + n * 200 + h * 32 + g * 8);
      floatx4 sacc[4];
#pragma unroll
      for (int rt = 0; rt < 4; ++rt) {
        const bf16x8 kf = *(const bf16x8*)(Kn + (rt * 16 + nl) * 200 + h * 32 + g * 8);
        sacc[rt] = __builtin_amdgcn_mfma_f32_16x16x32_bf16(kf, qf, (floatx4){0.f, 0.f, 0.f, 0.f}, 0, 0, 0);
      }
      const float* brow = bias + (h * NTOK + ncl) * NTOK;
      const float* mrow = mask + ((size_t)wmask * NTOK + ncl) * NTOK;
      float L[4][4];
      float pmax = -1e30f;
#pragma unroll
      for (int rt = 0; rt < 3; ++rt) {
        const F4 b4 = *(const F4*)(brow + rt * 16 + g * 4);
        const F4 m4 = *(const F4*)(mrow + rt * 16 + g * 4);
#pragma unroll
        for (int r = 0; r < 4; ++r) {
          const float lv = fmaf(sacc[rt][r], tdl, (b4.f[r] + m4.f[r]) * dl2);
          L[rt][r] = lv;
          pmax = fmaxf(pmax, lv);
        }
      }
      {  // rt=3: only m=48 real (g==0, r==0)
        const float lv48 = fmaf(sacc[3][0], tdl, (brow[48] + mrow[48]) * dl2);
        L[3][0] = L[3][1] = L[3][2] = L[3][3] = -1e30f;
        if (g == 0) { L[3][0] = lv48; pmax = fmaxf(pmax, lv48); }
      }
      pmax = fmaxf(pmax, __shfl_xor(pmax, 16));
      pmax = fmaxf(pmax, __shfl_xor(pmax, 32));
      float psum = 0.f;
#pragma unroll
      for (int rt = 0; rt < 4; ++rt)
#pragma unroll
        for (int r = 0; r < 4; ++r) {
          const float e = exp2f(L[rt][r] - pmax);
          L[rt][r] = e;
          psum += e;
        }
      psum += __shfl_xor(psum, 16);
      psum += __shfl_xor(psum, 32);
      const float rinv = 1.0f / psum;
#pragma unroll
      for (int rt = 0; rt < 4; ++rt)
        st4bf(Pb + nl * 72 + rt * 16 + g * 4,
              L[rt][0] * rinv, L[rt][1] * rinv, L[rt][2] * rinv, L[rt][3] * rinv);
      floatx4 oacc[2];
      oacc[0] = (floatx4){0.f, 0.f, 0.f, 0.f};
      oacc[1] = (floatx4){0.f, 0.f, 0.f, 0.f};
#pragma unroll
      for (int ks = 0; ks < 2; ++ks) {
        const bf16x8 pf = *(const bf16x8*)(Pb + nl * 72 + ks * 32 + g * 8);
#pragma unroll
        for (int dt = 0; dt < 2; ++dt) {
          const bf16x8 vf = *(const bf16x8*)(Vt + (h * 32 + dt * 16 + nl) * 72 + ks * 32 + g * 8);
          oacc[dt] = __builtin_amdgcn_mfma_f32_16x16x32_bf16(vf, pf, oacc[dt], 0, 0, 0);
        }
      }
#pragma unroll
      for (int dt = 0; dt < 2; ++dt)
        st4bf(Xb + n * 200 + h * 32 + dt * 16 + g * 4,
              oacc[dt][0], oacc[dt][1], oacc[dt][2], oacc[dt][3]);
    }
  }
  __syncthreads();

  // ---- phase 4: out = AO @ Wp^T (out^T = Wp * AO^T), 12 tasks over 16 waves
  {
    float* outb = out + (size_t)b * (NTOK * CDIM);
    const u16* wpb = w_bf + 3 * (CDIM * CDIM);
    for (int o = wave; o < 12; o += 16) {
      const u16* wb = wpb + (o * 16 + nl) * CDIM + g * 8;
      floatx4 acc[4];
#pragma unroll
      for (int nt = 0; nt < 4; ++nt) acc[nt] = (floatx4){0.f, 0.f, 0.f, 0.f};
#pragma unroll
      for (int k = 0; k < 6; ++k) {
        const bf16x8 wf = *(const bf16x8*)(wb + k * 32);
#pragma unroll
        for (int nt = 0; nt < 4; ++nt) {
          const bf16x8 af = *(const bf16x8*)(Xb + (nt * 16 + nl) * 200 + k * 32 + g * 8);
          acc[nt] = __builtin_amdgcn_mfma_f32_16x16x32_bf16(wf, af, acc[nt], 0, 0, 0);
        }
      }
#pragma unroll
      for (int nt = 0; nt < 4; ++nt) {
        const int n = nt * 16 + nl;
        if (n < NTOK) {
          float4 v;
          v.x = acc[nt][0]; v.y = acc[nt][1]; v.z = acc[nt][2]; v.w = acc[nt][3];
          *(float4*)(outb + n * CDIM + o * 16 + g * 4) = v;
        }
      }
    }
  }
}

extern "C" void kernel_launch(void* const* d_in, const int* in_sizes, int n_in,
                              void* d_out, int out_size, void* d_ws, size_t ws_size,
                              hipStream_t stream) {
  const float* x    = (const float*)d_in[0];
  const float* mask = (const float*)d_in[1];
  const float* dl   = (const float*)d_in[2];
  const float* Wq   = (const float*)d_in[3];
  const float* Wk   = (const float*)d_in[4];
  const float* Wv   = (const float*)d_in[5];
  const float* Wp   = (const float*)d_in[6];
  const float* temp = (const float*)d_in[7];
  const float* rpb  = (const float*)d_in[8];
  const int*   rel  = (const int*)d_in[9];

  u16* w_bf = (u16*)d_ws;
  float* bias = (float*)((char*)d_ws + (size_t)4 * CDIM * CDIM * sizeof(u16));
  float* o = (float*)d_out;

  (void)hipFuncSetAttribute((const void*)wattn_main,
                            hipFuncAttributeMaxDynamicSharedMemorySize, LDS_BYTES);

  wprep<<<256, 256, 0, stream>>>(Wq, Wk, Wv, Wp, rpb, rel, w_bf, bias);
  wattn_main<<<8192, 1024, LDS_BYTES, stream>>>(x, mask, dl, temp, w_bf, bias, o);
}